// Round 5
// baseline (291.861 us; speedup 1.0000x reference)
//
#include <hip/hip_runtime.h>
#include <hip/hip_bf16.h>
#include <stdint.h>

using u16 = unsigned short;

typedef __attribute__((ext_vector_type(8))) short bf16x8;
typedef __attribute__((ext_vector_type(4))) float f32x4;

typedef const __attribute__((address_space(1))) unsigned int* gas_t;
typedef __attribute__((address_space(3))) unsigned int* las_t;

__device__ inline void g2l16(const u16* g, u16* l) {
  __builtin_amdgcn_global_load_lds((gas_t)g, (las_t)l, 16, 0, 0);
}

__device__ inline u16 f2b(float x) {
  union { float f; uint32_t u; } v; v.f = x;
  uint32_t r = (v.u + 0x7FFFu + ((v.u >> 16) & 1u)) >> 16;
  return (u16)r;
}
__device__ inline float b2f(u16 b) {
  union { uint32_t u; float f; } v; v.u = ((uint32_t)b) << 16;
  return v.f;
}
__device__ inline float b2f_lo(uint32_t p) {
  union { uint32_t u; float f; } v; v.u = p << 16; return v.f;
}
__device__ inline float b2f_hi(uint32_t p) {
  union { uint32_t u; float f; } v; v.u = p & 0xFFFF0000u; return v.f;
}

__device__ inline void store_out(float* p, float v) { *p = v; }
__device__ inline void store_out(u16* p, float v) { *p = f2b(v); }

// ---------------------------------------------------------------------------
// Core 128x128 GEMM tile body. C[M x N] = A[M x K] * Bt[N x K]^T + bias[M].
// BK=64, XOR-swizzled LDS (0 bank conflicts, verified R3).
// ---------------------------------------------------------------------------
template<typename OutT>
__device__ inline void gemm_tile_128(const u16* __restrict__ A,
                                     const u16* __restrict__ Bt,
                                     const float* __restrict__ bias,
                                     OutT* __restrict__ C,
                                     int m0, int n0, int N, int K,
                                     u16* As, u16* Bs)
{
  const int tid  = threadIdx.x;
  const int wave = tid >> 6;
  const int lane = tid & 63;
  const int wm = wave >> 1, wn = wave & 1;
  const int lr = lane & 15;
  const int lq = lane >> 4;
  const int x7 = lr & 7;

  const int srow = tid >> 3;
  const int sgc  = (tid & 7) ^ (srow & 7);
  const u16* gA = A  + (size_t)(m0 + srow) * K + sgc * 8;
  const u16* gB = Bt + (size_t)(n0 + srow) * K + sgc * 8;
  u16* dstA = As + wave * 512;
  u16* dstB = Bs + wave * 512;

  f32x4 acc[4][4];
  #pragma unroll
  for (int i = 0; i < 4; ++i)
    #pragma unroll
    for (int j = 0; j < 4; ++j)
      acc[i][j] = (f32x4){0.f, 0.f, 0.f, 0.f};

  for (int k0 = 0; k0 < K; k0 += 64) {
    #pragma unroll
    for (int s = 0; s < 4; ++s) {
      g2l16(gA + (size_t)(s * 32) * K + k0, dstA + s * 2048);
      g2l16(gB + (size_t)(s * 32) * K + k0, dstB + s * 2048);
    }
    __syncthreads();

    #pragma unroll
    for (int ks = 0; ks < 2; ++ks) {
      const int pa = (ks * 4 + lq) ^ x7;
      bf16x8 af[4], bfr[4];
      #pragma unroll
      for (int im = 0; im < 4; ++im)
        af[im] = *(const bf16x8*)&As[(wm * 64 + im * 16 + lr) * 64 + pa * 8];
      #pragma unroll
      for (int in = 0; in < 4; ++in)
        bfr[in] = *(const bf16x8*)&Bs[(wn * 64 + in * 16 + lr) * 64 + pa * 8];

      #pragma unroll
      for (int im = 0; im < 4; ++im)
        #pragma unroll
        for (int in = 0; in < 4; ++in)
          acc[im][in] = __builtin_amdgcn_mfma_f32_16x16x32_bf16(
              af[im], bfr[in], acc[im][in], 0, 0, 0);
    }
    __syncthreads();
  }

  #pragma unroll
  for (int im = 0; im < 4; ++im) {
    const int mbase = m0 + wm * 64 + im * 16 + lq * 4;
    #pragma unroll
    for (int in = 0; in < 4; ++in) {
      const int ncol = n0 + wn * 64 + in * 16 + lr;
      #pragma unroll
      for (int r = 0; r < 4; ++r) {
        const int m = mbase + r;
        store_out(C + (size_t)m * N + ncol, acc[im][in][r] + bias[m]);
      }
    }
  }
}

// keys GEMM (by<32) and Q GEMM (by>=32) in one dispatch, both bf16 out.
__global__ __launch_bounds__(256)
void gemm_dual(const u16* __restrict__ WIb, const u16* __restrict__ IT,
               const float* __restrict__ bim, u16* __restrict__ KEYS,
               const u16* __restrict__ WLb, const u16* __restrict__ PT,
               const float* __restrict__ bL, u16* __restrict__ Qb)
{
  __shared__ u16 As[128 * 64];
  __shared__ u16 Bs[128 * 64];
  const int by = blockIdx.y;
  const int n0 = blockIdx.x * 128;
  if (by < 32)
    gemm_tile_128<u16>(WIb, IT, bim, KEYS, by * 128, n0, 4096, 1024, As, Bs);
  else
    gemm_tile_128<u16>(WLb, PT, bL, Qb, (by - 32) * 128, n0, 4096, 1024, As, Bs);
}

// ---------------------------------------------------------------------------
// 64x128 tile GEMM (final, fp32 out -> 512 blocks). BK=64, swizzled.
// ---------------------------------------------------------------------------
template<typename OutT>
__global__ __launch_bounds__(256)
void gemm_bt_64(const u16* __restrict__ A, const u16* __restrict__ Bt,
                const float* __restrict__ bias, OutT* __restrict__ C,
                int M, int N, int K)
{
  __shared__ u16 As[64 * 64];
  __shared__ u16 Bs[128 * 64];

  const int tid  = threadIdx.x;
  const int wave = tid >> 6;
  const int lane = tid & 63;
  const int lr = lane & 15;
  const int lq = lane >> 4;
  const int x7 = lr & 7;

  const int m0 = blockIdx.y * 64;
  const int n0 = blockIdx.x * 128;

  const int srow = tid >> 3;
  const int sgc  = (tid & 7) ^ (srow & 7);
  const u16* gA = A  + (size_t)(m0 + srow) * K + sgc * 8;
  const u16* gB = Bt + (size_t)(n0 + srow) * K + sgc * 8;
  u16* dstA = As + wave * 512;
  u16* dstB = Bs + wave * 512;

  f32x4 acc[4][2];
  #pragma unroll
  for (int i = 0; i < 4; ++i)
    #pragma unroll
    for (int j = 0; j < 2; ++j)
      acc[i][j] = (f32x4){0.f, 0.f, 0.f, 0.f};

  for (int k0 = 0; k0 < K; k0 += 64) {
    #pragma unroll
    for (int s = 0; s < 2; ++s)
      g2l16(gA + (size_t)(s * 32) * K + k0, dstA + s * 2048);
    #pragma unroll
    for (int s = 0; s < 4; ++s)
      g2l16(gB + (size_t)(s * 32) * K + k0, dstB + s * 2048);
    __syncthreads();

    #pragma unroll
    for (int ks = 0; ks < 2; ++ks) {
      const int pa = (ks * 4 + lq) ^ x7;
      bf16x8 af[4], bfr[2];
      #pragma unroll
      for (int im = 0; im < 4; ++im)
        af[im] = *(const bf16x8*)&As[(im * 16 + lr) * 64 + pa * 8];
      #pragma unroll
      for (int in = 0; in < 2; ++in)
        bfr[in] = *(const bf16x8*)&Bs[(wave * 32 + in * 16 + lr) * 64 + pa * 8];

      #pragma unroll
      for (int im = 0; im < 4; ++im)
        #pragma unroll
        for (int in = 0; in < 2; ++in)
          acc[im][in] = __builtin_amdgcn_mfma_f32_16x16x32_bf16(
              af[im], bfr[in], acc[im][in], 0, 0, 0);
    }
    __syncthreads();
  }

  #pragma unroll
  for (int im = 0; im < 4; ++im) {
    const int mbase = m0 + im * 16 + lq * 4;
    #pragma unroll
    for (int in = 0; in < 2; ++in) {
      const int ncol = n0 + wave * 32 + in * 16 + lr;
      #pragma unroll
      for (int r = 0; r < 4; ++r) {
        const int m = mbase + r;
        store_out(C + (size_t)m * N + ncol, acc[im][in][r] + bias[m]);
      }
    }
  }
}

// ---------------------------------------------------------------------------
// LDS-free transposes: each thread owns a 4x4 sub-tile, register transpose.
// fp32 [R x C] -> bf16 [C x R]; block covers a 64x64 tile (16 elems/thread).
// ---------------------------------------------------------------------------
__global__ __launch_bounds__(256)
void cast_transpose2(const float* __restrict__ in0, u16* __restrict__ out0,
                     const float* __restrict__ in1, u16* __restrict__ out1,
                     int R, int C)
{
  const float* in = blockIdx.z ? in1 : in0;
  u16* out = blockIdx.z ? out1 : out0;
  const int c0 = blockIdx.x * 64 + (threadIdx.x & 15) * 4;
  const int r0 = blockIdx.y * 64 + (threadIdx.x >> 4) * 4;
  float4 v[4];
  #pragma unroll
  for (int i = 0; i < 4; ++i)
    v[i] = *(const float4*)&in[(size_t)(r0 + i) * C + c0];
  const float* f = (const float*)v;   // f[i*4+j] = elem[r0+i][c0+j]
  #pragma unroll
  for (int j = 0; j < 4; ++j) {
    ushort4 o;
    o.x = f2b(f[0 * 4 + j]); o.y = f2b(f[1 * 4 + j]);
    o.z = f2b(f[2 * 4 + j]); o.w = f2b(f[3 * 4 + j]);
    *(ushort4*)&out[(size_t)(c0 + j) * R + r0] = o;
  }
}

// bf16 [R x C] -> bf16 [C x R], same structure
__global__ __launch_bounds__(256)
void transpose_u16(const u16* __restrict__ in, u16* __restrict__ out,
                   int R, int C)
{
  const int c0 = blockIdx.x * 64 + (threadIdx.x & 15) * 4;
  const int r0 = blockIdx.y * 64 + (threadIdx.x >> 4) * 4;
  ushort4 v[4];
  #pragma unroll
  for (int i = 0; i < 4; ++i)
    v[i] = *(const ushort4*)&in[(size_t)(r0 + i) * C + c0];
  const u16* e = (const u16*)v;
  #pragma unroll
  for (int j = 0; j < 4; ++j) {
    ushort4 o;
    o.x = e[0 * 4 + j]; o.y = e[1 * 4 + j];
    o.z = e[2 * 4 + j]; o.w = e[3 * 4 + j];
    *(ushort4*)&out[(size_t)(c0 + j) * R + r0] = o;
  }
}

// all three weight casts in one dispatch
__global__ __launch_bounds__(256)
void cast_weights(const float4* __restrict__ wim, const float4* __restrict__ wl,
                  const float4* __restrict__ wf, ushort4* __restrict__ wimb,
                  ushort4* __restrict__ wlb, ushort4* __restrict__ wfb)
{
  int i = blockIdx.x * 256 + threadIdx.x;
  const float4* src; ushort4* dst;
  if (i < 1048576)      { src = wim; dst = wimb; }
  else if (i < 1310720) { src = wl;  dst = wlb;  i -= 1048576; }
  else                  { src = wf;  dst = wfb;  i -= 1310720; }
  const float4 v = src[i];
  ushort4 o;
  o.x = f2b(v.x); o.y = f2b(v.y); o.z = f2b(v.z); o.w = f2b(v.w);
  dst[i] = o;
}

// spart[cb][h][n] = sum_{c in 32-chunk cb} Q[c][n] * keys[h*1024+c][n]
// 2 n's per thread; grid (8, 32) = 256 blocks.
__global__ __launch_bounds__(256)
void score_partial(const u16* __restrict__ keys, const u16* __restrict__ Qb,
                   float* __restrict__ spart)
{
  const int n  = (blockIdx.x * 256 + threadIdx.x) * 2;
  const int cb = blockIdx.y;
  const int c0 = cb * 32;
  float2 s[4];
  #pragma unroll
  for (int h = 0; h < 4; ++h) s[h] = make_float2(0.f, 0.f);
  #pragma unroll 8
  for (int c = c0; c < c0 + 32; ++c) {
    const uint32_t qv = *(const uint32_t*)&Qb[(size_t)c * 4096 + n];
    const float q0 = b2f_lo(qv), q1 = b2f_hi(qv);
    #pragma unroll
    for (int h = 0; h < 4; ++h) {
      const uint32_t kv = *(const uint32_t*)&keys[((size_t)((h << 10) + c)) * 4096 + n];
      s[h].x = fmaf(q0, b2f_lo(kv), s[h].x);
      s[h].y = fmaf(q1, b2f_hi(kv), s[h].y);
    }
  }
  #pragma unroll
  for (int h = 0; h < 4; ++h)
    *(float2*)&spart[((size_t)cb * 4 + h) * 4096 + n] = s[h];
}

// reduce 32 partials, scale 1/32, softmax over 4 heads -> weightmap
__global__ __launch_bounds__(256)
void softmax_h(const float* __restrict__ spart, float* __restrict__ wmap)
{
  const int n = blockIdx.x * 256 + threadIdx.x;
  float s[4] = {0.f, 0.f, 0.f, 0.f};
  for (int cb = 0; cb < 32; ++cb)
    #pragma unroll
    for (int h = 0; h < 4; ++h)
      s[h] += spart[((size_t)cb * 4 + h) * 4096 + n];
  #pragma unroll
  for (int h = 0; h < 4; ++h) s[h] *= 0.03125f;
  const float m = fmaxf(fmaxf(s[0], s[1]), fmaxf(s[2], s[3]));
  const float e0 = expf(s[0] - m), e1 = expf(s[1] - m);
  const float e2 = expf(s[2] - m), e3 = expf(s[3] - m);
  const float inv = 1.f / (e0 + e1 + e2 + e3);
  wmap[n] = e0 * inv; wmap[4096 + n] = e1 * inv;
  wmap[8192 + n] = e2 * inv; wmap[12288 + n] = e3 * inv;
}

// z = sum_h w[h][n]*keys[h][c][n]; t = z + Q; LayerNorm over n; bf16 out.
// 4 n's per thread via uint2/float4 loads.
__global__ __launch_bounds__(256)
void z_ln(const u16* __restrict__ keys, const u16* __restrict__ Qb,
          const float* __restrict__ w, const float* __restrict__ g,
          const float* __restrict__ bb, u16* __restrict__ fused)
{
  const int c  = blockIdx.x;
  const int tx = threadIdx.x;
  float t[16];
  float s = 0.f, s2 = 0.f;
  #pragma unroll
  for (int j = 0; j < 4; ++j) {
    const int n = tx * 4 + j * 1024;
    const uint2 qv = *(const uint2*)&Qb[(size_t)c * 4096 + n];
    float z0 = 0.f, z1 = 0.f, z2 = 0.f, z3 = 0.f;
    #pragma unroll
    for (int h = 0; h < 4; ++h) {
      const uint2 kv = *(const uint2*)&keys[((size_t)((h << 10) + c)) * 4096 + n];
      const float4 wv = *(const float4*)&w[h * 4096 + n];
      z0 = fmaf(wv.x, b2f_lo(kv.x), z0);
      z1 = fmaf(wv.y, b2f_hi(kv.x), z1);
      z2 = fmaf(wv.z, b2f_lo(kv.y), z2);
      z3 = fmaf(wv.w, b2f_hi(kv.y), z3);
    }
    const float v0 = z0 + b2f_lo(qv.x);
    const float v1 = z1 + b2f_hi(qv.x);
    const float v2 = z2 + b2f_lo(qv.y);
    const float v3 = z3 + b2f_hi(qv.y);
    t[4 * j] = v0; t[4 * j + 1] = v1; t[4 * j + 2] = v2; t[4 * j + 3] = v3;
    s += (v0 + v1) + (v2 + v3);
    s2 = fmaf(v0, v0, fmaf(v1, v1, fmaf(v2, v2, fmaf(v3, v3, s2))));
  }
  #pragma unroll
  for (int o = 32; o > 0; o >>= 1) {
    s  += __shfl_down(s, o);
    s2 += __shfl_down(s2, o);
  }
  __shared__ float rbuf[8];
  const int wave = tx >> 6, lane = tx & 63;
  if (lane == 0) { rbuf[wave] = s; rbuf[4 + wave] = s2; }
  __syncthreads();
  s  = rbuf[0] + rbuf[1] + rbuf[2] + rbuf[3];
  s2 = rbuf[4] + rbuf[5] + rbuf[6] + rbuf[7];
  const float mu  = s * (1.f / 4096.f);
  const float var = s2 * (1.f / 4096.f) - mu * mu;
  const float rs  = rsqrtf(var + 1e-5f);
  #pragma unroll
  for (int j = 0; j < 4; ++j) {
    const int n = tx * 4 + j * 1024;
    const float4 gv = *(const float4*)&g[n];
    const float4 bv = *(const float4*)&bb[n];
    ushort4 o;
    o.x = f2b((t[4 * j]     - mu) * rs * gv.x + bv.x);
    o.y = f2b((t[4 * j + 1] - mu) * rs * gv.y + bv.y);
    o.z = f2b((t[4 * j + 2] - mu) * rs * gv.z + bv.z);
    o.w = f2b((t[4 * j + 3] - mu) * rs * gv.w + bv.w);
    *(ushort4*)&fused[(size_t)c * 4096 + n] = o;
  }
}

extern "C" void kernel_launch(void* const* d_in, const int* in_sizes, int n_in,
                              void* d_out, int out_size, void* d_ws, size_t ws_size,
                              hipStream_t stream)
{
  const float* P   = (const float*)d_in[0];
  const float* I   = (const float*)d_in[1];
  const float* Wim = (const float*)d_in[2];
  const float* bim = (const float*)d_in[3];
  const float* WL  = (const float*)d_in[4];
  const float* bL  = (const float*)d_in[5];
  const float* lng = (const float*)d_in[6];
  const float* lnb = (const float*)d_in[7];
  const float* Wf  = (const float*)d_in[8];
  const float* bf_ = (const float*)d_in[9];
  float* out = (float*)d_out;

  char* ws = (char*)d_ws;
  u16*   PT     = (u16*)(ws + 0);                      //  8 MB [4096 x 1024]
  u16*   IT     = (u16*)(ws + (size_t)8  * 1048576);   //  8 MB
  u16*   WLb    = (u16*)(ws + (size_t)16 * 1048576);   //  2 MB
  u16*   WIb    = (u16*)(ws + (size_t)18 * 1048576);   //  8 MB
  u16*   WFb    = (u16*)(ws + (size_t)26 * 1048576);   //  2 MB
  u16*   Qb     = (u16*)(ws + (size_t)28 * 1048576);   //  8 MB [1024 x 4096]
  u16*   KEYS   = (u16*)(ws + (size_t)36 * 1048576);   // 32 MB [4096 x 4096]
  float* SPART  = (float*)(ws + (size_t)68 * 1048576); //  2 MB [32 x 4 x 4096]
  u16*   FUSED  = (u16*)(ws + (size_t)70 * 1048576);   //  8 MB [1024 x 4096]
  u16*   FUSEDT = (u16*)(ws + (size_t)78 * 1048576);   //  8 MB [4096 x 1024]

  const dim3 b256(256);

  // P,I fp32 -> bf16 transposed [4096 x 1024]; 64x64 tiles, LDS-free
  cast_transpose2<<<dim3(64, 16, 2), b256, 0, stream>>>(P, PT, I, IT, 1024, 4096);
  cast_weights<<<6144, b256, 0, stream>>>((const float4*)Wim, (const float4*)WL,
                                          (const float4*)Wf, (ushort4*)WIb,
                                          (ushort4*)WLb, (ushort4*)WFb);

  // keys [4096x4096] + Q [1024x4096] bf16 in one dispatch (1280 blocks)
  gemm_dual<<<dim3(32, 40), b256, 0, stream>>>(WIb, IT, bim, KEYS, WLb, PT, bL, Qb);

  // score partials -> softmax -> weightmap (into d_out tail)
  score_partial<<<dim3(8, 32), b256, 0, stream>>>(KEYS, Qb, SPART);
  float* wmap = out + (size_t)1024 * 4096;
  softmax_h<<<16, b256, 0, stream>>>(SPART, wmap);

  // z + residual + LayerNorm -> bf16, then transpose for final GEMM
  z_ln<<<1024, b256, 0, stream>>>(KEYS, Qb, wmap, lng, lnb, FUSED);
  transpose_u16<<<dim3(64, 16), b256, 0, stream>>>(FUSED, FUSEDT, 1024, 4096);

  // out = W_f * fused + b_f  [1024 x 4096] fp32
  gemm_bt_64<float><<<dim3(32, 16), b256, 0, stream>>>(WFb, FUSEDT, bf_, out, 1024, 4096, 1024);
}

// Round 6
// 258.197 us; speedup vs baseline: 1.1304x; 1.1304x over previous
//
#include <hip/hip_runtime.h>
#include <hip/hip_bf16.h>
#include <stdint.h>

using u16 = unsigned short;

typedef __attribute__((ext_vector_type(8))) short bf16x8;
typedef __attribute__((ext_vector_type(4))) float f32x4;

typedef const __attribute__((address_space(1))) unsigned int* gas_t;
typedef __attribute__((address_space(3))) unsigned int* las_t;

__device__ inline void g2l16(const u16* g, u16* l) {
  __builtin_amdgcn_global_load_lds((gas_t)g, (las_t)l, 16, 0, 0);
}

__device__ inline u16 f2b(float x) {
  union { float f; uint32_t u; } v; v.f = x;
  uint32_t r = (v.u + 0x7FFFu + ((v.u >> 16) & 1u)) >> 16;
  return (u16)r;
}
__device__ inline float b2f(u16 b) {
  union { uint32_t u; float f; } v; v.u = ((uint32_t)b) << 16;
  return v.f;
}

__device__ inline void store_out(float* p, float v) { *p = v; }
__device__ inline void store_out(u16* p, float v) { *p = f2b(v); }

// ---------------------------------------------------------------------------
// C[M x N] = A[M x K](bf16) * Bt[N x K](bf16)^T + bias[M]
// 128x128 tile, BK=64, XOR-swizzled LDS (conflict-free, verified R3).
// ---------------------------------------------------------------------------
template<typename OutT>
__global__ __launch_bounds__(256)
void gemm_bt(const u16* __restrict__ A, const u16* __restrict__ Bt,
             const float* __restrict__ bias, OutT* __restrict__ C,
             int M, int N, int K)
{
  __shared__ u16 As[128 * 64];
  __shared__ u16 Bs[128 * 64];

  const int tid  = threadIdx.x;
  const int wave = tid >> 6;
  const int lane = tid & 63;
  const int wm = wave >> 1, wn = wave & 1;
  const int lr = lane & 15;
  const int lq = lane >> 4;
  const int x7 = lr & 7;

  const int m0 = blockIdx.y * 128;
  const int n0 = blockIdx.x * 128;

  const int srow = tid >> 3;
  const int sgc  = (tid & 7) ^ (srow & 7);
  const u16* gA = A  + (size_t)(m0 + srow) * K + sgc * 8;
  const u16* gB = Bt + (size_t)(n0 + srow) * K + sgc * 8;
  u16* dstA = As + wave * 512;
  u16* dstB = Bs + wave * 512;

  f32x4 acc[4][4];
  #pragma unroll
  for (int i = 0; i < 4; ++i)
    #pragma unroll
    for (int j = 0; j < 4; ++j)
      acc[i][j] = (f32x4){0.f, 0.f, 0.f, 0.f};

  for (int k0 = 0; k0 < K; k0 += 64) {
    #pragma unroll
    for (int s = 0; s < 4; ++s) {
      g2l16(gA + (size_t)(s * 32) * K + k0, dstA + s * 2048);
      g2l16(gB + (size_t)(s * 32) * K + k0, dstB + s * 2048);
    }
    __syncthreads();

    #pragma unroll
    for (int ks = 0; ks < 2; ++ks) {
      const int pa = (ks * 4 + lq) ^ x7;
      bf16x8 af[4], bfr[4];
      #pragma unroll
      for (int im = 0; im < 4; ++im)
        af[im] = *(const bf16x8*)&As[(wm * 64 + im * 16 + lr) * 64 + pa * 8];
      #pragma unroll
      for (int in = 0; in < 4; ++in)
        bfr[in] = *(const bf16x8*)&Bs[(wn * 64 + in * 16 + lr) * 64 + pa * 8];

      #pragma unroll
      for (int im = 0; im < 4; ++im)
        #pragma unroll
        for (int in = 0; in < 4; ++in)
          acc[im][in] = __builtin_amdgcn_mfma_f32_16x16x32_bf16(
              af[im], bfr[in], acc[im][in], 0, 0, 0);
    }
    __syncthreads();
  }

  #pragma unroll
  for (int im = 0; im < 4; ++im) {
    const int mbase = m0 + wm * 64 + im * 16 + lq * 4;
    #pragma unroll
    for (int in = 0; in < 4; ++in) {
      const int ncol = n0 + wn * 64 + in * 16 + lr;
      #pragma unroll
      for (int r = 0; r < 4; ++r) {
        const int m = mbase + r;
        store_out(C + (size_t)m * N + ncol, acc[im][in][r] + bias[m]);
      }
    }
  }
}

// ---------------------------------------------------------------------------
// 64x128 tile variant (M=1024 GEMMs -> 512 blocks). BK=64, swizzled.
// ---------------------------------------------------------------------------
template<typename OutT>
__global__ __launch_bounds__(256)
void gemm_bt_64(const u16* __restrict__ A, const u16* __restrict__ Bt,
                const float* __restrict__ bias, OutT* __restrict__ C,
                int M, int N, int K)
{
  __shared__ u16 As[64 * 64];
  __shared__ u16 Bs[128 * 64];

  const int tid  = threadIdx.x;
  const int wave = tid >> 6;
  const int lane = tid & 63;
  const int lr = lane & 15;
  const int lq = lane >> 4;
  const int x7 = lr & 7;

  const int m0 = blockIdx.y * 64;
  const int n0 = blockIdx.x * 128;

  const int srow = tid >> 3;
  const int sgc  = (tid & 7) ^ (srow & 7);
  const u16* gA = A  + (size_t)(m0 + srow) * K + sgc * 8;
  const u16* gB = Bt + (size_t)(n0 + srow) * K + sgc * 8;
  u16* dstA = As + wave * 512;
  u16* dstB = Bs + wave * 512;

  f32x4 acc[4][2];
  #pragma unroll
  for (int i = 0; i < 4; ++i)
    #pragma unroll
    for (int j = 0; j < 2; ++j)
      acc[i][j] = (f32x4){0.f, 0.f, 0.f, 0.f};

  for (int k0 = 0; k0 < K; k0 += 64) {
    #pragma unroll
    for (int s = 0; s < 2; ++s)
      g2l16(gA + (size_t)(s * 32) * K + k0, dstA + s * 2048);
    #pragma unroll
    for (int s = 0; s < 4; ++s)
      g2l16(gB + (size_t)(s * 32) * K + k0, dstB + s * 2048);
    __syncthreads();

    #pragma unroll
    for (int ks = 0; ks < 2; ++ks) {
      const int pa = (ks * 4 + lq) ^ x7;
      bf16x8 af[4], bfr[2];
      #pragma unroll
      for (int im = 0; im < 4; ++im)
        af[im] = *(const bf16x8*)&As[(im * 16 + lr) * 64 + pa * 8];
      #pragma unroll
      for (int in = 0; in < 2; ++in)
        bfr[in] = *(const bf16x8*)&Bs[(wave * 32 + in * 16 + lr) * 64 + pa * 8];

      #pragma unroll
      for (int im = 0; im < 4; ++im)
        #pragma unroll
        for (int in = 0; in < 2; ++in)
          acc[im][in] = __builtin_amdgcn_mfma_f32_16x16x32_bf16(
              af[im], bfr[in], acc[im][in], 0, 0, 0);
    }
    __syncthreads();
  }

  #pragma unroll
  for (int im = 0; im < 4; ++im) {
    const int mbase = m0 + im * 16 + lq * 4;
    #pragma unroll
    for (int in = 0; in < 2; ++in) {
      const int ncol = n0 + wave * 32 + in * 16 + lr;
      #pragma unroll
      for (int r = 0; r < 4; ++r) {
        const int m = mbase + r;
        store_out(C + (size_t)m * N + ncol, acc[im][in][r] + bias[m]);
      }
    }
  }
}

// fp32 [R x C] -> bf16 [C x R], two sources selected by blockIdx.z
__global__ __launch_bounds__(256)
void cast_transpose2(const float* __restrict__ in0, u16* __restrict__ out0,
                     const float* __restrict__ in1, u16* __restrict__ out1,
                     int R, int C)
{
  const float* in = blockIdx.z ? in1 : in0;
  u16* out = blockIdx.z ? out1 : out0;
  __shared__ u16 tile[32][33];
  const int c0 = blockIdx.x * 32, r0 = blockIdx.y * 32;
  const int tx = threadIdx.x & 31, ty = threadIdx.x >> 5;
  #pragma unroll
  for (int k = 0; k < 4; ++k)
    tile[ty + 8 * k][tx] = f2b(in[(size_t)(r0 + ty + 8 * k) * C + c0 + tx]);
  __syncthreads();
  #pragma unroll
  for (int k = 0; k < 4; ++k)
    out[(size_t)(c0 + ty + 8 * k) * R + r0 + tx] = tile[tx][ty + 8 * k];
}

// bf16 [R x C] -> bf16 [C x R]
__global__ __launch_bounds__(256)
void transpose_u16(const u16* __restrict__ in, u16* __restrict__ out,
                   int R, int C)
{
  __shared__ u16 tile[32][33];
  const int c0 = blockIdx.x * 32, r0 = blockIdx.y * 32;
  const int tx = threadIdx.x & 31, ty = threadIdx.x >> 5;
  #pragma unroll
  for (int k = 0; k < 4; ++k)
    tile[ty + 8 * k][tx] = in[(size_t)(r0 + ty + 8 * k) * C + c0 + tx];
  __syncthreads();
  #pragma unroll
  for (int k = 0; k < 4; ++k)
    out[(size_t)(c0 + ty + 8 * k) * R + r0 + tx] = tile[tx][ty + 8 * k];
}

// all three weight casts in one dispatch
__global__ __launch_bounds__(256)
void cast_weights(const float4* __restrict__ wim, const float4* __restrict__ wl,
                  const float4* __restrict__ wf, ushort4* __restrict__ wimb,
                  ushort4* __restrict__ wlb, ushort4* __restrict__ wfb)
{
  int i = blockIdx.x * 256 + threadIdx.x;
  const float4* src; ushort4* dst;
  if (i < 1048576)      { src = wim; dst = wimb; }
  else if (i < 1310720) { src = wl;  dst = wlb;  i -= 1048576; }
  else                  { src = wf;  dst = wfb;  i -= 1310720; }
  const float4 v = src[i];
  ushort4 o;
  o.x = f2b(v.x); o.y = f2b(v.y); o.z = f2b(v.z); o.w = f2b(v.w);
  dst[i] = o;
}

// spart[cb][h][n] = sum_{c in 32-chunk cb} Q[c][n] * keys[h*1024+c][n]
// grid (16, 32) = 512 blocks (2 blocks/CU), unrolled for load pipelining.
__global__ __launch_bounds__(256)
void score_partial(const u16* __restrict__ keys, const float* __restrict__ Q,
                   float* __restrict__ spart)
{
  const int n  = blockIdx.x * 256 + threadIdx.x;
  const int cb = blockIdx.y;
  const int c0 = cb * 32;
  float s[4] = {0.f, 0.f, 0.f, 0.f};
  #pragma unroll 8
  for (int c = c0; c < c0 + 32; ++c) {
    const float q = Q[(size_t)c * 4096 + n];
    #pragma unroll
    for (int h = 0; h < 4; ++h)
      s[h] = fmaf(q, b2f(keys[((size_t)((h << 10) + c)) * 4096 + n]), s[h]);
  }
  #pragma unroll
  for (int h = 0; h < 4; ++h)
    spart[((size_t)cb * 4 + h) * 4096 + n] = s[h];
}

// reduce 32 partials, scale 1/32, softmax over 4 heads -> weightmap
__global__ __launch_bounds__(256)
void softmax_h(const float* __restrict__ spart, float* __restrict__ wmap)
{
  const int n = blockIdx.x * 256 + threadIdx.x;
  float s[4] = {0.f, 0.f, 0.f, 0.f};
  for (int cb = 0; cb < 32; ++cb)
    #pragma unroll
    for (int h = 0; h < 4; ++h)
      s[h] += spart[((size_t)cb * 4 + h) * 4096 + n];
  #pragma unroll
  for (int h = 0; h < 4; ++h) s[h] *= 0.03125f;
  const float m = fmaxf(fmaxf(s[0], s[1]), fmaxf(s[2], s[3]));
  const float e0 = expf(s[0] - m), e1 = expf(s[1] - m);
  const float e2 = expf(s[2] - m), e3 = expf(s[3] - m);
  const float inv = 1.f / (e0 + e1 + e2 + e3);
  wmap[n] = e0 * inv; wmap[4096 + n] = e1 * inv;
  wmap[8192 + n] = e2 * inv; wmap[12288 + n] = e3 * inv;
}

// z = sum_h w[h][n]*keys[h][c][n]; t = z + Q; LayerNorm over n; bf16 out
__global__ __launch_bounds__(256)
void z_ln(const u16* __restrict__ keys, const float* __restrict__ Q,
          const float* __restrict__ w, const float* __restrict__ g,
          const float* __restrict__ bb, u16* __restrict__ fused)
{
  const int c  = blockIdx.x;
  const int tx = threadIdx.x;
  float t[16];
  float s = 0.f, s2 = 0.f;
  #pragma unroll
  for (int j = 0; j < 16; ++j) {
    const int n = tx + j * 256;
    const float q = Q[(size_t)c * 4096 + n];
    float z = 0.f;
    #pragma unroll
    for (int h = 0; h < 4; ++h)
      z = fmaf(w[h * 4096 + n], b2f(keys[((size_t)((h << 10) + c)) * 4096 + n]), z);
    const float v = z + q;
    t[j] = v; s += v; s2 = fmaf(v, v, s2);
  }
  #pragma unroll
  for (int o = 32; o > 0; o >>= 1) {
    s  += __shfl_down(s, o);
    s2 += __shfl_down(s2, o);
  }
  __shared__ float rbuf[8];
  const int wave = tx >> 6, lane = tx & 63;
  if (lane == 0) { rbuf[wave] = s; rbuf[4 + wave] = s2; }
  __syncthreads();
  s  = rbuf[0] + rbuf[1] + rbuf[2] + rbuf[3];
  s2 = rbuf[4] + rbuf[5] + rbuf[6] + rbuf[7];
  const float mu  = s * (1.f / 4096.f);
  const float var = s2 * (1.f / 4096.f) - mu * mu;
  const float rs  = rsqrtf(var + 1e-5f);
  #pragma unroll
  for (int j = 0; j < 16; ++j) {
    const int n = tx + j * 256;
    fused[(size_t)c * 4096 + n] = f2b((t[j] - mu) * rs * g[n] + bb[n]);
  }
}

extern "C" void kernel_launch(void* const* d_in, const int* in_sizes, int n_in,
                              void* d_out, int out_size, void* d_ws, size_t ws_size,
                              hipStream_t stream)
{
  const float* P   = (const float*)d_in[0];
  const float* I   = (const float*)d_in[1];
  const float* Wim = (const float*)d_in[2];
  const float* bim = (const float*)d_in[3];
  const float* WL  = (const float*)d_in[4];
  const float* bL  = (const float*)d_in[5];
  const float* lng = (const float*)d_in[6];
  const float* lnb = (const float*)d_in[7];
  const float* Wf  = (const float*)d_in[8];
  const float* bf_ = (const float*)d_in[9];
  float* out = (float*)d_out;

  char* ws = (char*)d_ws;
  u16*   PT     = (u16*)(ws + 0);                      //  8 MB [4096 x 1024]
  u16*   IT     = (u16*)(ws + (size_t)8  * 1048576);   //  8 MB
  u16*   WLb    = (u16*)(ws + (size_t)16 * 1048576);   //  2 MB
  u16*   WIb    = (u16*)(ws + (size_t)18 * 1048576);   //  8 MB
  u16*   WFb    = (u16*)(ws + (size_t)26 * 1048576);   //  2 MB
  float* Q      = (float*)(ws + (size_t)28 * 1048576); // 16 MB [1024 x 4096] fp32
  u16*   KEYS   = (u16*)(ws + (size_t)44 * 1048576);   // 32 MB [4096 x 4096] bf16
  float* SPART  = (float*)(ws + (size_t)76 * 1048576); //  2 MB [32 x 4 x 4096]
  u16*   FUSED  = (u16*)(ws + (size_t)78 * 1048576);   //  8 MB [1024 x 4096]
  u16*   FUSEDT = (u16*)(ws + (size_t)86 * 1048576);   //  8 MB [4096 x 1024]

  const dim3 b256(256);

  cast_transpose2<<<dim3(128, 32, 2), b256, 0, stream>>>(P, PT, I, IT, 1024, 4096);
  cast_weights<<<6144, b256, 0, stream>>>((const float4*)Wim, (const float4*)WL,
                                          (const float4*)Wf, (ushort4*)WIb,
                                          (ushort4*)WLb, (ushort4*)WFb);

  // Q = W_L * P + b_L   [1024 x 4096] fp32  (64x128 tiles -> 512 blocks)
  gemm_bt_64<float><<<dim3(32, 16), b256, 0, stream>>>(WLb, PT, bL, Q, 1024, 4096, 1024);
  // keys = W_img * I + b_img  [4096 x 4096] bf16 (128x128 tiles -> 1024 blocks)
  gemm_bt<u16><<<dim3(32, 32), b256, 0, stream>>>(WIb, IT, bim, KEYS, 4096, 4096, 1024);

  // score partials (512 blocks) -> softmax -> weightmap (into d_out tail)
  score_partial<<<dim3(16, 32), b256, 0, stream>>>(KEYS, Q, SPART);
  float* wmap = out + (size_t)1024 * 4096;
  softmax_h<<<16, b256, 0, stream>>>(SPART, wmap);

  // z + residual + LayerNorm -> bf16, then transpose for final GEMM
  z_ln<<<1024, b256, 0, stream>>>(KEYS, Q, wmap, lng, lnb, FUSED);
  transpose_u16<<<dim3(128, 32), b256, 0, stream>>>(FUSED, FUSEDT, 1024, 4096);

  // out = W_f * fused + b_f  [1024 x 4096] fp32
  gemm_bt_64<float><<<dim3(32, 16), b256, 0, stream>>>(WFb, FUSEDT, bf_, out, 1024, 4096, 1024);
}

// Round 7
// 219.041 us; speedup vs baseline: 1.3324x; 1.1788x over previous
//
#include <hip/hip_runtime.h>
#include <hip/hip_bf16.h>
#include <stdint.h>

using u16 = unsigned short;

typedef __attribute__((ext_vector_type(8))) short bf16x8;
typedef __attribute__((ext_vector_type(4))) float f32x4;

typedef const __attribute__((address_space(1))) unsigned int* gas_t;
typedef __attribute__((address_space(3))) unsigned int* las_t;

__device__ inline void g2l16(const u16* g, u16* l) {
  __builtin_amdgcn_global_load_lds((gas_t)g, (las_t)l, 16, 0, 0);
}

__device__ inline u16 f2b(float x) {
  union { float f; uint32_t u; } v; v.f = x;
  uint32_t r = (v.u + 0x7FFFu + ((v.u >> 16) & 1u)) >> 16;
  return (u16)r;
}
__device__ inline float b2f(u16 b) {
  union { uint32_t u; float f; } v; v.u = ((uint32_t)b) << 16;
  return v.f;
}

__device__ inline void store_out(float* p, float v) { *p = v; }
__device__ inline void store_out(u16* p, float v) { *p = f2b(v); }

// ---------------------------------------------------------------------------
// Core 128x128 GEMM tile. C[M x N] = A[M x K]*Bt[N x K]^T + bias[M].
// BK=64, XOR-swizzled LDS (0 conflicts, verified R3). N=4096, K=1024 fixed
// callers; keep generic ints.
// ---------------------------------------------------------------------------
template<typename OutT>
__device__ inline void gemm_tile_128(const u16* __restrict__ A,
                                     const u16* __restrict__ Bt,
                                     const float* __restrict__ bias,
                                     OutT* __restrict__ C,
                                     int m0, int n0, int N, int K,
                                     u16* As, u16* Bs)
{
  const int tid  = threadIdx.x;
  const int wave = tid >> 6;
  const int lane = tid & 63;
  const int wm = wave >> 1, wn = wave & 1;
  const int lr = lane & 15;
  const int lq = lane >> 4;
  const int x7 = lr & 7;

  const int srow = tid >> 3;
  const int sgc  = (tid & 7) ^ (srow & 7);
  const u16* gA = A  + (size_t)(m0 + srow) * K + sgc * 8;
  const u16* gB = Bt + (size_t)(n0 + srow) * K + sgc * 8;
  u16* dstA = As + wave * 512;
  u16* dstB = Bs + wave * 512;

  f32x4 acc[4][4];
  #pragma unroll
  for (int i = 0; i < 4; ++i)
    #pragma unroll
    for (int j = 0; j < 4; ++j)
      acc[i][j] = (f32x4){0.f, 0.f, 0.f, 0.f};

  for (int k0 = 0; k0 < K; k0 += 64) {
    #pragma unroll
    for (int s = 0; s < 4; ++s) {
      g2l16(gA + (size_t)(s * 32) * K + k0, dstA + s * 2048);
      g2l16(gB + (size_t)(s * 32) * K + k0, dstB + s * 2048);
    }
    __syncthreads();

    #pragma unroll
    for (int ks = 0; ks < 2; ++ks) {
      const int pa = (ks * 4 + lq) ^ x7;
      bf16x8 af[4], bfr[4];
      #pragma unroll
      for (int im = 0; im < 4; ++im)
        af[im] = *(const bf16x8*)&As[(wm * 64 + im * 16 + lr) * 64 + pa * 8];
      #pragma unroll
      for (int in = 0; in < 4; ++in)
        bfr[in] = *(const bf16x8*)&Bs[(wn * 64 + in * 16 + lr) * 64 + pa * 8];

      #pragma unroll
      for (int im = 0; im < 4; ++im)
        #pragma unroll
        for (int in = 0; in < 4; ++in)
          acc[im][in] = __builtin_amdgcn_mfma_f32_16x16x32_bf16(
              af[im], bfr[in], acc[im][in], 0, 0, 0);
    }
    __syncthreads();
  }

  #pragma unroll
  for (int im = 0; im < 4; ++im) {
    const int mbase = m0 + wm * 64 + im * 16 + lq * 4;
    #pragma unroll
    for (int in = 0; in < 4; ++in) {
      const int ncol = n0 + wn * 64 + in * 16 + lr;
      #pragma unroll
      for (int r = 0; r < 4; ++r) {
        const int m = mbase + r;
        store_out(C + (size_t)m * N + ncol, acc[im][in][r] + bias[m]);
      }
    }
  }
}

// keys [4096x4096] (by<32) and Q [1024x4096] (by>=32) in one dispatch.
// Pointer-select + SINGLE tile-body call => no double-inline VGPR bloat (R5).
__global__ __launch_bounds__(256)
void gemm_keys_q(const u16* __restrict__ WIb, const u16* __restrict__ IT,
                 const float* __restrict__ bim, u16* __restrict__ KEYS,
                 const u16* __restrict__ WLb, const u16* __restrict__ PT,
                 const float* __restrict__ bL, u16* __restrict__ Qb)
{
  __shared__ u16 As[128 * 64];
  __shared__ u16 Bs[128 * 64];
  const int by = blockIdx.y;
  const bool keys = (by < 32);
  const u16*   A    = keys ? WIb : WLb;
  const u16*   Bt   = keys ? IT  : PT;
  const float* bias = keys ? bim : bL;
  u16*         C    = keys ? KEYS : Qb;
  const int m0 = (by & 31) * 128;
  const int n0 = blockIdx.x * 128;
  gemm_tile_128<u16>(A, Bt, bias, C, m0, n0, 4096, 1024, As, Bs);
}

// ---------------------------------------------------------------------------
// 64x128 tile GEMM for the final fp32 GEMM (512 blocks). BK=64, swizzled.
// ---------------------------------------------------------------------------
template<typename OutT>
__global__ __launch_bounds__(256)
void gemm_bt_64(const u16* __restrict__ A, const u16* __restrict__ Bt,
                const float* __restrict__ bias, OutT* __restrict__ C,
                int M, int N, int K)
{
  __shared__ u16 As[64 * 64];
  __shared__ u16 Bs[128 * 64];

  const int tid  = threadIdx.x;
  const int wave = tid >> 6;
  const int lane = tid & 63;
  const int lr = lane & 15;
  const int lq = lane >> 4;
  const int x7 = lr & 7;

  const int m0 = blockIdx.y * 64;
  const int n0 = blockIdx.x * 128;

  const int srow = tid >> 3;
  const int sgc  = (tid & 7) ^ (srow & 7);
  const u16* gA = A  + (size_t)(m0 + srow) * K + sgc * 8;
  const u16* gB = Bt + (size_t)(n0 + srow) * K + sgc * 8;
  u16* dstA = As + wave * 512;
  u16* dstB = Bs + wave * 512;

  f32x4 acc[4][2];
  #pragma unroll
  for (int i = 0; i < 4; ++i)
    #pragma unroll
    for (int j = 0; j < 2; ++j)
      acc[i][j] = (f32x4){0.f, 0.f, 0.f, 0.f};

  for (int k0 = 0; k0 < K; k0 += 64) {
    #pragma unroll
    for (int s = 0; s < 2; ++s)
      g2l16(gA + (size_t)(s * 32) * K + k0, dstA + s * 2048);
    #pragma unroll
    for (int s = 0; s < 4; ++s)
      g2l16(gB + (size_t)(s * 32) * K + k0, dstB + s * 2048);
    __syncthreads();

    #pragma unroll
    for (int ks = 0; ks < 2; ++ks) {
      const int pa = (ks * 4 + lq) ^ x7;
      bf16x8 af[4], bfr[2];
      #pragma unroll
      for (int im = 0; im < 4; ++im)
        af[im] = *(const bf16x8*)&As[(im * 16 + lr) * 64 + pa * 8];
      #pragma unroll
      for (int in = 0; in < 2; ++in)
        bfr[in] = *(const bf16x8*)&Bs[(wave * 32 + in * 16 + lr) * 64 + pa * 8];

      #pragma unroll
      for (int im = 0; im < 4; ++im)
        #pragma unroll
        for (int in = 0; in < 2; ++in)
          acc[im][in] = __builtin_amdgcn_mfma_f32_16x16x32_bf16(
              af[im], bfr[in], acc[im][in], 0, 0, 0);
    }
    __syncthreads();
  }

  #pragma unroll
  for (int im = 0; im < 4; ++im) {
    const int mbase = m0 + im * 16 + lq * 4;
    #pragma unroll
    for (int in = 0; in < 2; ++in) {
      const int ncol = n0 + wave * 32 + in * 16 + lr;
      #pragma unroll
      for (int r = 0; r < 4; ++r) {
        const int m = mbase + r;
        store_out(C + (size_t)m * N + ncol, acc[im][in][r] + bias[m]);
      }
    }
  }
}

// ---------------------------------------------------------------------------
// Prep: P,I fp32->bf16 transposed  PLUS  3 weight casts, one dispatch.
// Flat grid: blocks [0,8192) transpose (z = bid>>12), [8192,14336) cast.
// ---------------------------------------------------------------------------
__global__ __launch_bounds__(256)
void prep(const float* __restrict__ P, u16* __restrict__ PT,
          const float* __restrict__ I, u16* __restrict__ IT,
          const float4* __restrict__ wim, const float4* __restrict__ wl,
          const float4* __restrict__ wf, ushort4* __restrict__ wimb,
          ushort4* __restrict__ wlb, ushort4* __restrict__ wfb)
{
  const int bid = blockIdx.x;
  if (bid < 8192) {
    const int z   = bid >> 12;          // 0: P, 1: I
    const int rem = bid & 4095;
    const int bx  = rem & 127;          // 128 col-tiles
    const int byy = rem >> 7;           // 32 row-tiles
    const float* in = z ? I : P;
    u16* out = z ? IT : PT;
    __shared__ u16 tile[32][33];
    const int c0 = bx * 32, r0 = byy * 32;
    const int tx = threadIdx.x & 31, ty = threadIdx.x >> 5;
    #pragma unroll
    for (int k = 0; k < 4; ++k)
      tile[ty + 8 * k][tx] = f2b(in[(size_t)(r0 + ty + 8 * k) * 4096 + c0 + tx]);
    __syncthreads();
    #pragma unroll
    for (int k = 0; k < 4; ++k)
      out[(size_t)(c0 + ty + 8 * k) * 1024 + r0 + tx] = tile[tx][ty + 8 * k];
  } else {
    int i = (bid - 8192) * 256 + threadIdx.x;
    const float4* src; ushort4* dst;
    if (i < 1048576)      { src = wim; dst = wimb; }
    else if (i < 1310720) { src = wl;  dst = wlb;  i -= 1048576; }
    else                  { src = wf;  dst = wfb;  i -= 1310720; }
    const float4 v = src[i];
    ushort4 o;
    o.x = f2b(v.x); o.y = f2b(v.y); o.z = f2b(v.z); o.w = f2b(v.w);
    dst[i] = o;
  }
}

// bf16 [R x C] -> bf16 [C x R]
__global__ __launch_bounds__(256)
void transpose_u16(const u16* __restrict__ in, u16* __restrict__ out,
                   int R, int C)
{
  __shared__ u16 tile[32][33];
  const int c0 = blockIdx.x * 32, r0 = blockIdx.y * 32;
  const int tx = threadIdx.x & 31, ty = threadIdx.x >> 5;
  #pragma unroll
  for (int k = 0; k < 4; ++k)
    tile[ty + 8 * k][tx] = in[(size_t)(r0 + ty + 8 * k) * C + c0 + tx];
  __syncthreads();
  #pragma unroll
  for (int k = 0; k < 4; ++k)
    out[(size_t)(c0 + ty + 8 * k) * R + r0 + tx] = tile[tx][ty + 8 * k];
}

// spart[cb][h][n] = sum_{c in 128-chunk cb} Q[c][n]*keys[h*1024+c][n]
// R3-proven form: grid (16,8), non-unrolled outer loop. Q now bf16.
__global__ __launch_bounds__(256)
void score_partial(const u16* __restrict__ keys, const u16* __restrict__ Qb,
                   float* __restrict__ spart)
{
  const int n  = blockIdx.x * 256 + threadIdx.x;
  const int cb = blockIdx.y;
  const int c0 = cb * 128;
  float s[4] = {0.f, 0.f, 0.f, 0.f};
  for (int c = c0; c < c0 + 128; ++c) {
    const float q = b2f(Qb[(size_t)c * 4096 + n]);
    #pragma unroll
    for (int h = 0; h < 4; ++h)
      s[h] = fmaf(q, b2f(keys[((size_t)((h << 10) + c)) * 4096 + n]), s[h]);
  }
  #pragma unroll
  for (int h = 0; h < 4; ++h)
    spart[((size_t)cb * 4 + h) * 4096 + n] = s[h];
}

// reduce 8 partials, scale 1/32, softmax over 4 heads -> weightmap
__global__ __launch_bounds__(256)
void softmax_h(const float* __restrict__ spart, float* __restrict__ wmap)
{
  const int n = blockIdx.x * 256 + threadIdx.x;
  float s[4] = {0.f, 0.f, 0.f, 0.f};
  #pragma unroll
  for (int cb = 0; cb < 8; ++cb)
    #pragma unroll
    for (int h = 0; h < 4; ++h)
      s[h] += spart[((size_t)cb * 4 + h) * 4096 + n];
  #pragma unroll
  for (int h = 0; h < 4; ++h) s[h] *= 0.03125f;
  const float m = fmaxf(fmaxf(s[0], s[1]), fmaxf(s[2], s[3]));
  const float e0 = expf(s[0] - m), e1 = expf(s[1] - m);
  const float e2 = expf(s[2] - m), e3 = expf(s[3] - m);
  const float inv = 1.f / (e0 + e1 + e2 + e3);
  wmap[n] = e0 * inv; wmap[4096 + n] = e1 * inv;
  wmap[8192 + n] = e2 * inv; wmap[12288 + n] = e3 * inv;
}

// z = sum_h w[h][n]*keys[h][c][n]; t = z + Q; LayerNorm over n; bf16 out
__global__ __launch_bounds__(256)
void z_ln(const u16* __restrict__ keys, const u16* __restrict__ Qb,
          const float* __restrict__ w, const float* __restrict__ g,
          const float* __restrict__ bb, u16* __restrict__ fused)
{
  const int c  = blockIdx.x;
  const int tx = threadIdx.x;
  float t[16];
  float s = 0.f, s2 = 0.f;
  #pragma unroll
  for (int j = 0; j < 16; ++j) {
    const int n = tx + j * 256;
    const float q = b2f(Qb[(size_t)c * 4096 + n]);
    float z = 0.f;
    #pragma unroll
    for (int h = 0; h < 4; ++h)
      z = fmaf(w[h * 4096 + n], b2f(keys[((size_t)((h << 10) + c)) * 4096 + n]), z);
    const float v = z + q;
    t[j] = v; s += v; s2 = fmaf(v, v, s2);
  }
  #pragma unroll
  for (int o = 32; o > 0; o >>= 1) {
    s  += __shfl_down(s, o);
    s2 += __shfl_down(s2, o);
  }
  __shared__ float rbuf[8];
  const int wave = tx >> 6, lane = tx & 63;
  if (lane == 0) { rbuf[wave] = s; rbuf[4 + wave] = s2; }
  __syncthreads();
  s  = rbuf[0] + rbuf[1] + rbuf[2] + rbuf[3];
  s2 = rbuf[4] + rbuf[5] + rbuf[6] + rbuf[7];
  const float mu  = s * (1.f / 4096.f);
  const float var = s2 * (1.f / 4096.f) - mu * mu;
  const float rs  = rsqrtf(var + 1e-5f);
  #pragma unroll
  for (int j = 0; j < 16; ++j) {
    const int n = tx + j * 256;
    fused[(size_t)c * 4096 + n] = f2b((t[j] - mu) * rs * g[n] + bb[n]);
  }
}

extern "C" void kernel_launch(void* const* d_in, const int* in_sizes, int n_in,
                              void* d_out, int out_size, void* d_ws, size_t ws_size,
                              hipStream_t stream)
{
  const float* P   = (const float*)d_in[0];
  const float* I   = (const float*)d_in[1];
  const float* Wim = (const float*)d_in[2];
  const float* bim = (const float*)d_in[3];
  const float* WL  = (const float*)d_in[4];
  const float* bL  = (const float*)d_in[5];
  const float* lng = (const float*)d_in[6];
  const float* lnb = (const float*)d_in[7];
  const float* Wf  = (const float*)d_in[8];
  const float* bf_ = (const float*)d_in[9];
  float* out = (float*)d_out;

  char* ws = (char*)d_ws;
  u16*   PT     = (u16*)(ws + 0);                      //  8 MB [4096 x 1024]
  u16*   IT     = (u16*)(ws + (size_t)8  * 1048576);   //  8 MB
  u16*   WLb    = (u16*)(ws + (size_t)16 * 1048576);   //  2 MB
  u16*   WIb    = (u16*)(ws + (size_t)18 * 1048576);   //  8 MB
  u16*   WFb    = (u16*)(ws + (size_t)26 * 1048576);   //  2 MB
  u16*   Qb     = (u16*)(ws + (size_t)28 * 1048576);   //  8 MB [1024 x 4096] bf16
  u16*   KEYS   = (u16*)(ws + (size_t)36 * 1048576);   // 32 MB [4096 x 4096] bf16
  float* SPART  = (float*)(ws + (size_t)68 * 1048576); // 512 KB [8 x 4 x 4096]
  u16*   FUSED  = (u16*)(ws + (size_t)70 * 1048576);   //  8 MB [1024 x 4096]
  u16*   FUSEDT = (u16*)(ws + (size_t)78 * 1048576);   //  8 MB [4096 x 1024]

  const dim3 b256(256);

  // all input casts/transposes in one dispatch (14336 blocks)
  prep<<<14336, b256, 0, stream>>>(P, PT, I, IT,
                                   (const float4*)Wim, (const float4*)WL,
                                   (const float4*)Wf, (ushort4*)WIb,
                                   (ushort4*)WLb, (ushort4*)WFb);

  // keys [4096x4096] + Q [1024x4096], both bf16, one dispatch (1280 blocks)
  gemm_keys_q<<<dim3(32, 40), b256, 0, stream>>>(WIb, IT, bim, KEYS,
                                                 WLb, PT, bL, Qb);

  // score partials (R3 form) -> softmax -> weightmap (into d_out tail)
  score_partial<<<dim3(16, 8), b256, 0, stream>>>(KEYS, Qb, SPART);
  float* wmap = out + (size_t)1024 * 4096;
  softmax_h<<<16, b256, 0, stream>>>(SPART, wmap);

  // z + residual + LayerNorm -> bf16, then transpose for final GEMM
  z_ln<<<1024, b256, 0, stream>>>(KEYS, Qb, wmap, lng, lnb, FUSED);
  transpose_u16<<<dim3(128, 32), b256, 0, stream>>>(FUSED, FUSEDT, 1024, 4096);

  // out = W_f * fused + b_f  [1024 x 4096] fp32
  gemm_bt_64<float><<<dim3(32, 16), b256, 0, stream>>>(WFb, FUSEDT, bf_, out, 1024, 4096, 1024);
}

// Round 8
// 210.403 us; speedup vs baseline: 1.3872x; 1.0411x over previous
//
#include <hip/hip_runtime.h>
#include <hip/hip_bf16.h>
#include <stdint.h>

using u16 = unsigned short;

typedef __attribute__((ext_vector_type(8))) short bf16x8;
typedef __attribute__((ext_vector_type(4))) float f32x4;

typedef const __attribute__((address_space(1))) unsigned int* gas_t;
typedef __attribute__((address_space(3))) unsigned int* las_t;

__device__ inline void g2l16(const u16* g, u16* l) {
  __builtin_amdgcn_global_load_lds((gas_t)g, (las_t)l, 16, 0, 0);
}

__device__ inline u16 f2b(float x) {
  union { float f; uint32_t u; } v; v.f = x;
  uint32_t r = (v.u + 0x7FFFu + ((v.u >> 16) & 1u)) >> 16;
  return (u16)r;
}
__device__ inline float b2f(u16 b) {
  union { uint32_t u; float f; } v; v.u = ((uint32_t)b) << 16;
  return v.f;
}
__device__ inline float b2f_lo(uint32_t p) {
  union { uint32_t u; float f; } v; v.u = p << 16; return v.f;
}
__device__ inline float b2f_hi(uint32_t p) {
  union { uint32_t u; float f; } v; v.u = p & 0xFFFF0000u; return v.f;
}

__device__ inline void store_out(float* p, float v) { *p = v; }
__device__ inline void store_out(u16* p, float v) { *p = f2b(v); }

// ---------------------------------------------------------------------------
// Core 128x128 GEMM tile. BK=64, XOR-swizzled LDS (0 conflicts, verified R3).
// ---------------------------------------------------------------------------
template<typename OutT>
__device__ inline void gemm_tile_128(const u16* __restrict__ A,
                                     const u16* __restrict__ Bt,
                                     const float* __restrict__ bias,
                                     OutT* __restrict__ C,
                                     int m0, int n0, int N, int K,
                                     u16* As, u16* Bs)
{
  const int tid  = threadIdx.x;
  const int wave = tid >> 6;
  const int lane = tid & 63;
  const int wm = wave >> 1, wn = wave & 1;
  const int lr = lane & 15;
  const int lq = lane >> 4;
  const int x7 = lr & 7;

  const int srow = tid >> 3;
  const int sgc  = (tid & 7) ^ (srow & 7);
  const u16* gA = A  + (size_t)(m0 + srow) * K + sgc * 8;
  const u16* gB = Bt + (size_t)(n0 + srow) * K + sgc * 8;
  u16* dstA = As + wave * 512;
  u16* dstB = Bs + wave * 512;

  f32x4 acc[4][4];
  #pragma unroll
  for (int i = 0; i < 4; ++i)
    #pragma unroll
    for (int j = 0; j < 4; ++j)
      acc[i][j] = (f32x4){0.f, 0.f, 0.f, 0.f};

  for (int k0 = 0; k0 < K; k0 += 64) {
    #pragma unroll
    for (int s = 0; s < 4; ++s) {
      g2l16(gA + (size_t)(s * 32) * K + k0, dstA + s * 2048);
      g2l16(gB + (size_t)(s * 32) * K + k0, dstB + s * 2048);
    }
    __syncthreads();

    #pragma unroll
    for (int ks = 0; ks < 2; ++ks) {
      const int pa = (ks * 4 + lq) ^ x7;
      bf16x8 af[4], bfr[4];
      #pragma unroll
      for (int im = 0; im < 4; ++im)
        af[im] = *(const bf16x8*)&As[(wm * 64 + im * 16 + lr) * 64 + pa * 8];
      #pragma unroll
      for (int in = 0; in < 4; ++in)
        bfr[in] = *(const bf16x8*)&Bs[(wn * 64 + in * 16 + lr) * 64 + pa * 8];

      #pragma unroll
      for (int im = 0; im < 4; ++im)
        #pragma unroll
        for (int in = 0; in < 4; ++in)
          acc[im][in] = __builtin_amdgcn_mfma_f32_16x16x32_bf16(
              af[im], bfr[in], acc[im][in], 0, 0, 0);
    }
    __syncthreads();
  }

  #pragma unroll
  for (int im = 0; im < 4; ++im) {
    const int mbase = m0 + wm * 64 + im * 16 + lq * 4;
    #pragma unroll
    for (int in = 0; in < 4; ++in) {
      const int ncol = n0 + wn * 64 + in * 16 + lr;
      #pragma unroll
      for (int r = 0; r < 4; ++r) {
        const int m = mbase + r;
        store_out(C + (size_t)m * N + ncol, acc[im][in][r] + bias[m]);
      }
    }
  }
}

// keys [4096x4096] (by<32) and Q [1024x4096] (by>=32) in one dispatch.
// Pointer-select + SINGLE tile-body call => no double-inline VGPR bloat.
__global__ __launch_bounds__(256)
void gemm_keys_q(const u16* __restrict__ WIb, const u16* __restrict__ IT,
                 const float* __restrict__ bim, u16* __restrict__ KEYS,
                 const u16* __restrict__ WLb, const u16* __restrict__ PT,
                 const float* __restrict__ bL, u16* __restrict__ Qb)
{
  __shared__ u16 As[128 * 64];
  __shared__ u16 Bs[128 * 64];
  const int by = blockIdx.y;
  const bool keys = (by < 32);
  const u16*   A    = keys ? WIb : WLb;
  const u16*   Bt   = keys ? IT  : PT;
  const float* bias = keys ? bim : bL;
  u16*         C    = keys ? KEYS : Qb;
  const int m0 = (by & 31) * 128;
  const int n0 = blockIdx.x * 128;
  gemm_tile_128<u16>(A, Bt, bias, C, m0, n0, 4096, 1024, As, Bs);
}

// ---------------------------------------------------------------------------
// 64x128 tile GEMM for the final fp32 GEMM (512 blocks). BK=64, swizzled.
// ---------------------------------------------------------------------------
template<typename OutT>
__global__ __launch_bounds__(256)
void gemm_bt_64(const u16* __restrict__ A, const u16* __restrict__ Bt,
                const float* __restrict__ bias, OutT* __restrict__ C,
                int M, int N, int K)
{
  __shared__ u16 As[64 * 64];
  __shared__ u16 Bs[128 * 64];

  const int tid  = threadIdx.x;
  const int wave = tid >> 6;
  const int lane = tid & 63;
  const int lr = lane & 15;
  const int lq = lane >> 4;
  const int x7 = lr & 7;

  const int m0 = blockIdx.y * 64;
  const int n0 = blockIdx.x * 128;

  const int srow = tid >> 3;
  const int sgc  = (tid & 7) ^ (srow & 7);
  const u16* gA = A  + (size_t)(m0 + srow) * K + sgc * 8;
  const u16* gB = Bt + (size_t)(n0 + srow) * K + sgc * 8;
  u16* dstA = As + wave * 512;
  u16* dstB = Bs + wave * 512;

  f32x4 acc[4][2];
  #pragma unroll
  for (int i = 0; i < 4; ++i)
    #pragma unroll
    for (int j = 0; j < 2; ++j)
      acc[i][j] = (f32x4){0.f, 0.f, 0.f, 0.f};

  for (int k0 = 0; k0 < K; k0 += 64) {
    #pragma unroll
    for (int s = 0; s < 2; ++s)
      g2l16(gA + (size_t)(s * 32) * K + k0, dstA + s * 2048);
    #pragma unroll
    for (int s = 0; s < 4; ++s)
      g2l16(gB + (size_t)(s * 32) * K + k0, dstB + s * 2048);
    __syncthreads();

    #pragma unroll
    for (int ks = 0; ks < 2; ++ks) {
      const int pa = (ks * 4 + lq) ^ x7;
      bf16x8 af[4], bfr[2];
      #pragma unroll
      for (int im = 0; im < 4; ++im)
        af[im] = *(const bf16x8*)&As[(im * 16 + lr) * 64 + pa * 8];
      #pragma unroll
      for (int in = 0; in < 2; ++in)
        bfr[in] = *(const bf16x8*)&Bs[(wave * 32 + in * 16 + lr) * 64 + pa * 8];

      #pragma unroll
      for (int im = 0; im < 4; ++im)
        #pragma unroll
        for (int in = 0; in < 2; ++in)
          acc[im][in] = __builtin_amdgcn_mfma_f32_16x16x32_bf16(
              af[im], bfr[in], acc[im][in], 0, 0, 0);
    }
    __syncthreads();
  }

  #pragma unroll
  for (int im = 0; im < 4; ++im) {
    const int mbase = m0 + im * 16 + lq * 4;
    #pragma unroll
    for (int in = 0; in < 2; ++in) {
      const int ncol = n0 + wave * 32 + in * 16 + lr;
      #pragma unroll
      for (int r = 0; r < 4; ++r) {
        const int m = mbase + r;
        store_out(C + (size_t)m * N + ncol, acc[im][in][r] + bias[m]);
      }
    }
  }
}

// ---------------------------------------------------------------------------
// Prep: P,I fp32->bf16 transposed  PLUS  3 weight casts, one dispatch.
// ---------------------------------------------------------------------------
__global__ __launch_bounds__(256)
void prep(const float* __restrict__ P, u16* __restrict__ PT,
          const float* __restrict__ I, u16* __restrict__ IT,
          const float4* __restrict__ wim, const float4* __restrict__ wl,
          const float4* __restrict__ wf, ushort4* __restrict__ wimb,
          ushort4* __restrict__ wlb, ushort4* __restrict__ wfb)
{
  const int bid = blockIdx.x;
  if (bid < 8192) {
    const int z   = bid >> 12;          // 0: P, 1: I
    const int rem = bid & 4095;
    const int bx  = rem & 127;
    const int byy = rem >> 7;
    const float* in = z ? I : P;
    u16* out = z ? IT : PT;
    __shared__ u16 tile[32][33];
    const int c0 = bx * 32, r0 = byy * 32;
    const int tx = threadIdx.x & 31, ty = threadIdx.x >> 5;
    #pragma unroll
    for (int k = 0; k < 4; ++k)
      tile[ty + 8 * k][tx] = f2b(in[(size_t)(r0 + ty + 8 * k) * 4096 + c0 + tx]);
    __syncthreads();
    #pragma unroll
    for (int k = 0; k < 4; ++k)
      out[(size_t)(c0 + ty + 8 * k) * 1024 + r0 + tx] = tile[tx][ty + 8 * k];
  } else {
    int i = (bid - 8192) * 256 + threadIdx.x;
    const float4* src; ushort4* dst;
    if (i < 1048576)      { src = wim; dst = wimb; }
    else if (i < 1310720) { src = wl;  dst = wlb;  i -= 1048576; }
    else                  { src = wf;  dst = wfb;  i -= 1310720; }
    const float4 v = src[i];
    ushort4 o;
    o.x = f2b(v.x); o.y = f2b(v.y); o.z = f2b(v.z); o.w = f2b(v.w);
    dst[i] = o;
  }
}

// bf16 [R x C] -> bf16 [C x R]
__global__ __launch_bounds__(256)
void transpose_u16(const u16* __restrict__ in, u16* __restrict__ out,
                   int R, int C)
{
  __shared__ u16 tile[32][33];
  const int c0 = blockIdx.x * 32, r0 = blockIdx.y * 32;
  const int tx = threadIdx.x & 31, ty = threadIdx.x >> 5;
  #pragma unroll
  for (int k = 0; k < 4; ++k)
    tile[ty + 8 * k][tx] = in[(size_t)(r0 + ty + 8 * k) * C + c0 + tx];
  __syncthreads();
  #pragma unroll
  for (int k = 0; k < 4; ++k)
    out[(size_t)(c0 + ty + 8 * k) * R + r0 + tx] = tile[tx][ty + 8 * k];
}

// score[h][n] += (1/32)*sum_{c in 32-chunk} Q[c][n]*keys[h*1024+c][n]
// grid (16, 32) = 512 blocks; NO unroll pragma (R6's unroll-8 spilled).
__global__ __launch_bounds__(256)
void score_partial(const u16* __restrict__ keys, const u16* __restrict__ Qb,
                   float* __restrict__ score)
{
  const int n  = blockIdx.x * 256 + threadIdx.x;
  const int c0 = blockIdx.y * 32;
  float s[4] = {0.f, 0.f, 0.f, 0.f};
  for (int c = c0; c < c0 + 32; ++c) {
    const float q = b2f(Qb[(size_t)c * 4096 + n]);
    #pragma unroll
    for (int h = 0; h < 4; ++h)
      s[h] = fmaf(q, b2f(keys[((size_t)((h << 10) + c)) * 4096 + n]), s[h]);
  }
  #pragma unroll
  for (int h = 0; h < 4; ++h)
    atomicAdd(&score[h * 4096 + n], s[h] * 0.03125f);
}

// softmax over 4 heads -> weightmap
__global__ __launch_bounds__(256)
void softmax_h(const float* __restrict__ score, float* __restrict__ wmap)
{
  const int n = blockIdx.x * 256 + threadIdx.x;
  const float s0 = score[n], s1 = score[4096 + n];
  const float s2 = score[8192 + n], s3 = score[12288 + n];
  const float m = fmaxf(fmaxf(s0, s1), fmaxf(s2, s3));
  const float e0 = expf(s0 - m), e1 = expf(s1 - m);
  const float e2 = expf(s2 - m), e3 = expf(s3 - m);
  const float inv = 1.f / (e0 + e1 + e2 + e3);
  wmap[n] = e0 * inv; wmap[4096 + n] = e1 * inv;
  wmap[8192 + n] = e2 * inv; wmap[12288 + n] = e3 * inv;
}

// z = sum_h w[h][n]*keys[h][c][n]; t = z + Q; LayerNorm over n; bf16 out.
// 8 n's per thread: uint4 (16B) loads on Qb/keys, float4 on w/g/b.
__global__ __launch_bounds__(256)
void z_ln(const u16* __restrict__ keys, const u16* __restrict__ Qb,
          const float* __restrict__ w, const float* __restrict__ g,
          const float* __restrict__ bb, u16* __restrict__ fused)
{
  const int c  = blockIdx.x;
  const int tx = threadIdx.x;
  float t[16];
  float s = 0.f, s2 = 0.f;
  #pragma unroll
  for (int j = 0; j < 2; ++j) {
    const int n = tx * 8 + j * 2048;
    const uint4 qv = *(const uint4*)&Qb[(size_t)c * 4096 + n];
    float z[8] = {0.f,0.f,0.f,0.f,0.f,0.f,0.f,0.f};
    #pragma unroll
    for (int h = 0; h < 4; ++h) {
      const uint4 kv = *(const uint4*)&keys[((size_t)((h << 10) + c)) * 4096 + n];
      const float4 w0 = *(const float4*)&w[h * 4096 + n];
      const float4 w1 = *(const float4*)&w[h * 4096 + n + 4];
      z[0] = fmaf(w0.x, b2f_lo(kv.x), z[0]);
      z[1] = fmaf(w0.y, b2f_hi(kv.x), z[1]);
      z[2] = fmaf(w0.z, b2f_lo(kv.y), z[2]);
      z[3] = fmaf(w0.w, b2f_hi(kv.y), z[3]);
      z[4] = fmaf(w1.x, b2f_lo(kv.z), z[4]);
      z[5] = fmaf(w1.y, b2f_hi(kv.z), z[5]);
      z[6] = fmaf(w1.z, b2f_lo(kv.w), z[6]);
      z[7] = fmaf(w1.w, b2f_hi(kv.w), z[7]);
    }
    const uint32_t qs[4] = {qv.x, qv.y, qv.z, qv.w};
    #pragma unroll
    for (int e = 0; e < 4; ++e) {
      const float v0 = z[2 * e]     + b2f_lo(qs[e]);
      const float v1 = z[2 * e + 1] + b2f_hi(qs[e]);
      t[8 * j + 2 * e]     = v0;
      t[8 * j + 2 * e + 1] = v1;
      s += v0 + v1;
      s2 = fmaf(v0, v0, fmaf(v1, v1, s2));
    }
  }
  #pragma unroll
  for (int o = 32; o > 0; o >>= 1) {
    s  += __shfl_down(s, o);
    s2 += __shfl_down(s2, o);
  }
  __shared__ float rbuf[8];
  const int wave = tx >> 6, lane = tx & 63;
  if (lane == 0) { rbuf[wave] = s; rbuf[4 + wave] = s2; }
  __syncthreads();
  s  = rbuf[0] + rbuf[1] + rbuf[2] + rbuf[3];
  s2 = rbuf[4] + rbuf[5] + rbuf[6] + rbuf[7];
  const float mu  = s * (1.f / 4096.f);
  const float var = s2 * (1.f / 4096.f) - mu * mu;
  const float rs  = rsqrtf(var + 1e-5f);
  #pragma unroll
  for (int j = 0; j < 2; ++j) {
    const int n = tx * 8 + j * 2048;
    #pragma unroll
    for (int q4 = 0; q4 < 2; ++q4) {
      const float4 gv = *(const float4*)&g[n + 4 * q4];
      const float4 bv = *(const float4*)&bb[n + 4 * q4];
      ushort4 o;
      o.x = f2b((t[8 * j + 4 * q4]     - mu) * rs * gv.x + bv.x);
      o.y = f2b((t[8 * j + 4 * q4 + 1] - mu) * rs * gv.y + bv.y);
      o.z = f2b((t[8 * j + 4 * q4 + 2] - mu) * rs * gv.z + bv.z);
      o.w = f2b((t[8 * j + 4 * q4 + 3] - mu) * rs * gv.w + bv.w);
      *(ushort4*)&fused[(size_t)c * 4096 + n + 4 * q4] = o;
    }
  }
}

extern "C" void kernel_launch(void* const* d_in, const int* in_sizes, int n_in,
                              void* d_out, int out_size, void* d_ws, size_t ws_size,
                              hipStream_t stream)
{
  const float* P   = (const float*)d_in[0];
  const float* I   = (const float*)d_in[1];
  const float* Wim = (const float*)d_in[2];
  const float* bim = (const float*)d_in[3];
  const float* WL  = (const float*)d_in[4];
  const float* bL  = (const float*)d_in[5];
  const float* lng = (const float*)d_in[6];
  const float* lnb = (const float*)d_in[7];
  const float* Wf  = (const float*)d_in[8];
  const float* bf_ = (const float*)d_in[9];
  float* out = (float*)d_out;

  char* ws = (char*)d_ws;
  u16*   PT     = (u16*)(ws + 0);                      //  8 MB [4096 x 1024]
  u16*   IT     = (u16*)(ws + (size_t)8  * 1048576);   //  8 MB
  u16*   WLb    = (u16*)(ws + (size_t)16 * 1048576);   //  2 MB
  u16*   WIb    = (u16*)(ws + (size_t)18 * 1048576);   //  8 MB
  u16*   WFb    = (u16*)(ws + (size_t)26 * 1048576);   //  2 MB
  u16*   Qb     = (u16*)(ws + (size_t)28 * 1048576);   //  8 MB [1024 x 4096]
  u16*   KEYS   = (u16*)(ws + (size_t)36 * 1048576);   // 32 MB [4096 x 4096]
  float* SCORE  = (float*)(ws + (size_t)68 * 1048576); // 64 KB [4 x 4096]
  u16*   FUSED  = (u16*)(ws + (size_t)70 * 1048576);   //  8 MB [1024 x 4096]
  u16*   FUSEDT = (u16*)(ws + (size_t)78 * 1048576);   //  8 MB [4096 x 1024]

  const dim3 b256(256);

  // all input casts/transposes in one dispatch (14336 blocks)
  prep<<<14336, b256, 0, stream>>>(P, PT, I, IT,
                                   (const float4*)Wim, (const float4*)WL,
                                   (const float4*)Wf, (ushort4*)WIb,
                                   (ushort4*)WLb, (ushort4*)WFb);

  // keys [4096x4096] + Q [1024x4096], both bf16, one dispatch (1280 blocks)
  gemm_keys_q<<<dim3(32, 40), b256, 0, stream>>>(WIb, IT, bim, KEYS,
                                                 WLb, PT, bL, Qb);

  // score (512 blocks, atomic accumulate) -> softmax -> weightmap
  hipMemsetAsync(SCORE, 0, 4 * 4096 * sizeof(float), stream);
  score_partial<<<dim3(16, 32), b256, 0, stream>>>(KEYS, Qb, SCORE);
  float* wmap = out + (size_t)1024 * 4096;
  softmax_h<<<16, b256, 0, stream>>>(SCORE, wmap);

  // z + residual + LayerNorm -> bf16 (8-wide), then transpose for final GEMM
  z_ln<<<1024, b256, 0, stream>>>(KEYS, Qb, wmap, lng, lnb, FUSED);
  transpose_u16<<<dim3(128, 32), b256, 0, stream>>>(FUSED, FUSEDT, 1024, 4096);

  // out = W_f * fused + b_f  [1024 x 4096] fp32
  gemm_bt_64<float><<<dim3(32, 16), b256, 0, stream>>>(WFb, FUSEDT, bf_, out, 1024, 4096, 1024);
}